// Round 9
// baseline (896.008 us; speedup 1.0000x reference)
//
#include <hip/hip_runtime.h>

#define N_NODES 100000
#define NPAD    100096      // 782 * 128
#define NTILES  782
#define G_GRAPHS 256
#define IN_F 162
#define HID 128
#define R_REL 5
#define L_LAYERS 2
#define M5 (R_REL * N_NODES)
#define KSEG0 192           // layer-0 segment width (162 padded to 192)
#define KC0   (6 * KSEG0)   // 1152 : logical K of layer-0 GEMM
#define KC1   (6 * HID)     // 768  : logical K of layer-1/2 GEMM

typedef __attribute__((ext_vector_type(8))) short bf16x8;
typedef __attribute__((ext_vector_type(4))) float f32x4;

__device__ __forceinline__ short f2bf(float f) {
    union { float f; unsigned u; } v; v.f = f;
    unsigned r = (v.u + 0x7fffu + ((v.u >> 16) & 1u)) >> 16;
    return (short)r;
}
__device__ __forceinline__ float bf2f(unsigned short u) {
    union { unsigned u; float f; } v; v.u = ((unsigned)u) << 16;
    return v.f;
}

// ---------------- CSR build, keyed by (relation, dst) ----------------
__global__ void k_count(const int* e0, const int* e1, const int* e2,
                        const int* e3, const int* e4, int* cnt, int E) {
    int gid = blockIdx.x * 256 + threadIdx.x;
    if (gid >= R_REL * E) return;
    int r = gid / E, e = gid - r * E;
    const int* ei = (r == 0) ? e0 : (r == 1) ? e1 : (r == 2) ? e2 : (r == 3) ? e3 : e4;
    atomicAdd(&cnt[r * N_NODES + ei[E + e]], 1);
}

__global__ __launch_bounds__(256) void k_scan1(const int* __restrict__ cnt,
                                               int* __restrict__ off, int* __restrict__ bsum) {
    __shared__ int ts[256];
    int t = threadIdx.x;
    int base = blockIdx.x * 1024 + t * 4;
    int v[4];
    #pragma unroll
    for (int j = 0; j < 4; j++) v[j] = (base + j < M5) ? cnt[base + j] : 0;
    int tsum = v[0] + v[1] + v[2] + v[3];
    ts[t] = tsum; __syncthreads();
    for (int o = 1; o < 256; o <<= 1) {
        int x = (t >= o) ? ts[t - o] : 0;
        __syncthreads();
        ts[t] += x;
        __syncthreads();
    }
    if (t == 255) bsum[blockIdx.x] = ts[255];
    int run = ts[t] - tsum;
    #pragma unroll
    for (int j = 0; j < 4; j++) { if (base + j < M5) off[base + j] = run; run += v[j]; }
}

__global__ __launch_bounds__(512) void k_scan2(int* bsum, int nblk) {
    __shared__ int ts[512];
    int t = threadIdx.x;
    int v = (t < nblk) ? bsum[t] : 0;
    ts[t] = v; __syncthreads();
    for (int o = 1; o < 512; o <<= 1) {
        int x = (t >= o) ? ts[t - o] : 0;
        __syncthreads();
        ts[t] += x;
        __syncthreads();
    }
    if (t < nblk) bsum[t] = ts[t] - v;   // exclusive
}

__global__ void k_scan3(const int* __restrict__ off, const int* __restrict__ bsum,
                        int* __restrict__ mstart, int* __restrict__ mcur,
                        const int* __restrict__ cnt, float* __restrict__ invc) {
    int i = blockIdx.x * 256 + threadIdx.x;
    if (i >= M5) return;
    int o = off[i] + bsum[i >> 10];
    mstart[i] = o;
    mcur[i] = o;
    int c = cnt[i];
    invc[i] = 1.0f / (float)max(c, 1);
    if (i == M5 - 1) mstart[M5] = o + c;
}

__global__ void k_fill(const int* e0, const int* e1, const int* e2,
                       const int* e3, const int* e4, int* mcur,
                       int* __restrict__ mrec, int E) {
    int gid = blockIdx.x * 256 + threadIdx.x;
    if (gid >= R_REL * E) return;
    int r = gid / E, e = gid - r * E;
    const int* ei = (r == 0) ? e0 : (r == 1) ? e1 : (r == 2) ? e2 : (r == 3) ? e3 : e4;
    int src = ei[e], dst = ei[E + e];
    int pos = atomicAdd(&mcur[r * N_NODES + dst], 1);
    mrec[pos] = src;
}

// ---------------- X fp32 -> bf16, padded [NPAD][192] ----------------
__global__ void k_castX(const float* __restrict__ X, unsigned short* __restrict__ Xb) {
    int gid = blockIdx.x * 256 + threadIdx.x;
    if (gid >= NPAD * KSEG0) return;
    int row = gid / KSEG0, k = gid - row * KSEG0;
    float v = (row < N_NODES && k < IN_F) ? X[(size_t)row * IN_F + k] : 0.f;
    Xb[gid] = (unsigned short)f2bf(v);
}

// ---------------- weight transpose: Wt[col][KCAT] with seg-concat K ----------------
__global__ void k_tw0(const float* __restrict__ root0, const float* __restrict__ W0,
                      short* __restrict__ out) {
    int gid = blockIdx.x * 256 + threadIdx.x;   // 128 * 1152
    if (gid >= 128 * KC0) return;
    int col = gid / KC0;
    int kk = gid - col * KC0;
    int chunk = kk / KSEG0, k = kk - chunk * KSEG0;
    float v = 0.f;
    if (k < IN_F)
        v = (chunk == 0) ? root0[k * HID + col]
                         : W0[((size_t)(chunk - 1) * IN_F + k) * HID + col];
    out[gid] = f2bf(v);
}

__global__ void k_twl(const float* __restrict__ rootl, const float* __restrict__ Wl,
                      short* __restrict__ out) {
    int gid = blockIdx.x * 256 + threadIdx.x;   // 2 * 128 * 768
    if (gid >= L_LAYERS * 128 * KC1) return;
    int l = gid / (128 * KC1);
    int rem = gid - l * 128 * KC1;
    int col = rem / KC1;
    int kk = rem - col * KC1;
    int chunk = kk / HID, k = kk - chunk * HID;
    float v = (chunk == 0) ? rootl[((size_t)l * HID + k) * HID + col]
                           : Wl[(((size_t)l * R_REL + (chunk - 1)) * HID + k) * HID + col];
    out[gid] = f2bf(v);
}

// ---------------- fused gather+GEMM, 8-wave / high-concurrency gather ----------------
// h'[row][0:128] = relu( [A0 | Z1..Z5] @ Wt^T + bias ). Z never hits global.
// 512 threads: 8 waves in a 4x2 grid of 32x64 MFMA tiles (acc[2][4]).
// Gather: 32 chains/block of 4 consecutive dsts; edges walked flat with a
// copy-free 2-deep pipeline (named A/B buffers), one uint4 (16B/lane = full
// 256B row) per edge (+uint2 for layer-0's extra 128B). CSR meta + edge
// indices staged in LDS so only the row load touches HBM/L3.
template<int KSEG>
__global__ __launch_bounds__(512)
void gemm_fused(const unsigned short* __restrict__ A0, const short* __restrict__ Wt,
                const float* __restrict__ bias,
                const int* __restrict__ mstart, const int* __restrict__ mrec,
                const float* __restrict__ invc,
                unsigned short* __restrict__ Hout) {
    constexpr int KS = KSEG / 32;                 // k-steps per segment (6 or 4)
    constexpr int KCAT = 6 * KSEG;
    constexpr int SA = (KSEG == 192) ? 184 : 136; // Z-tile LDS row stride (shorts)
    constexpr int EBUF = 320;                     // staged edge indices per segment
    __shared__ short Zs[128 * SA + 16];           // +16: L0 k=5 quad=3 read spill
    __shared__ int   sMS[5 * 129];                // mstart slices (block dsts, 5 segs)
    __shared__ float sMW[5 * 128];                // invc slices
    __shared__ int   sE[EBUF];                    // per-segment edge indices

    const int row0 = blockIdx.x * 128;
    const int tid = threadIdx.x;
    const int lane = tid & 63, wv = tid >> 6;     // 8 waves
    const int quad = lane >> 4, l16 = lane & 15;
    const int wr0 = (wv >> 1) * 32, wc0 = (wv & 1) * 64;
    const int local0 = (tid >> 4) * 4;            // chain's first dst (4 consecutive)

    // ---- stage CSR meta for the whole block (overlaps seg0 MFMA) ----
    for (int i = tid; i < 5 * 129; i += 512) {
        int seg = i / 129, o = i - seg * 129;
        sMS[i] = mstart[seg * N_NODES + min(row0 + o, N_NODES)];
    }
    for (int i = tid; i < 5 * 128; i += 512) {
        int seg = i >> 7, o = i & 127;
        int d = row0 + o;
        sMW[i] = (d < N_NODES) ? invc[seg * N_NODES + d] : 0.f;
    }
    if constexpr (KSEG == 192) {                  // zero L0's unwritten cols 168..183
        for (int i = tid; i < 128 * 16; i += 512)
            Zs[(i >> 4) * SA + 168 + (i & 15)] = 0;
    }

    const unsigned short* a0p = A0 + (size_t)(row0 + wr0 + l16) * KSEG + quad * 8;
    const short* Bp = Wt + (size_t)(wc0 + l16) * KCAT + quad * 8;

    f32x4 acc[2][4];
    #pragma unroll
    for (int i = 0; i < 2; i++)
        #pragma unroll
        for (int j = 0; j < 4; j++) acc[i][j] = (f32x4){0.f, 0.f, 0.f, 0.f};

    // ---- seg0: root term, A direct from global, 1-deep register dbuf ----
    bf16x8 ac[2], bc[4], an[2], bn[4];
    #pragma unroll
    for (int i = 0; i < 2; i++) ac[i] = *(const bf16x8*)(a0p + (size_t)i * 16 * KSEG);
    #pragma unroll
    for (int j = 0; j < 4; j++) bc[j] = *(const bf16x8*)(Bp + (size_t)j * 16 * KCAT);
    #pragma unroll
    for (int t = 0; t < KS; t++) {
        if (t + 1 < KS) {
            #pragma unroll
            for (int i = 0; i < 2; i++)
                an[i] = *(const bf16x8*)(a0p + (size_t)i * 16 * KSEG + (t + 1) * 32);
            #pragma unroll
            for (int j = 0; j < 4; j++)
                bn[j] = *(const bf16x8*)(Bp + (size_t)j * 16 * KCAT + (t + 1) * 32);
        }
        #pragma unroll
        for (int i = 0; i < 2; i++)
            #pragma unroll
            for (int j = 0; j < 4; j++)
                acc[i][j] = __builtin_amdgcn_mfma_f32_16x16x32_bf16(ac[i], bc[j], acc[i][j], 0, 0, 0);
        if (t + 1 < KS) {
            #pragma unroll
            for (int i = 0; i < 2; i++) ac[i] = an[i];
            #pragma unroll
            for (int j = 0; j < 4; j++) bc[j] = bn[j];
        }
    }
    __syncthreads();   // meta (and L0 zero-cols) staged

    // ---- relation segments ----
    for (int sg = 0; sg < R_REL; sg++) {
        const int tb = (1 + sg) * KS;
        #pragma unroll
        for (int j = 0; j < 4; j++)
            bc[j] = *(const bf16x8*)(Bp + (size_t)j * 16 * KCAT + tb * 32);

        // stage this segment's edge-index run (contiguous in mrec) into LDS
        const int blo = sMS[sg * 129];
        {
            int cnt = sMS[sg * 129 + 128] - blo;
            if (cnt > EBUF) cnt = EBUF;
            for (int i = tid; i < cnt; i += 512) sE[i] = mrec[blo + i];
        }
        __syncthreads();   // sE ready; prior MFMA done reading Zs

        // ---- gather: flat edge walk, 4 consecutive dsts per 16-lane chain ----
        {
            const int jlo = sMS[sg * 129 + local0];
            const int jhi = sMS[sg * 129 + local0 + 4];
            int di = 0;
            int nextb = sMS[sg * 129 + local0 + 1];
            float a0 = 0.f, a1 = 0.f, a2 = 0.f, a3 = 0.f,
                  a4 = 0.f, a5 = 0.f, a6 = 0.f, a7 = 0.f;
            float e8 = 0.f, e9 = 0.f, e10 = 0.f, e11 = 0.f;   // L0 extra cols
            uint4 vA = {0, 0, 0, 0}, vB = {0, 0, 0, 0};
            uint2 uA = {0, 0}, uB = {0, 0};

            auto LD = [&](int j, uint4& v, uint2& u) {
                int jj = j - blo;
                int src = (jj < EBUF) ? sE[jj] : mrec[j];
                const unsigned short* r = A0 + (size_t)src * KSEG;
                v = *(const uint4*)(r + l16 * 8);
                if constexpr (KSEG == 192) u = *(const uint2*)(r + 128 + l16 * 4);
            };
            auto CONSUME = [&](const uint4& v, const uint2& u) {
                a0 += bf2f((unsigned short)(v.x & 0xffff));
                a1 += bf2f((unsigned short)(v.x >> 16));
                a2 += bf2f((unsigned short)(v.y & 0xffff));
                a3 += bf2f((unsigned short)(v.y >> 16));
                a4 += bf2f((unsigned short)(v.z & 0xffff));
                a5 += bf2f((unsigned short)(v.z >> 16));
                a6 += bf2f((unsigned short)(v.w & 0xffff));
                a7 += bf2f((unsigned short)(v.w >> 16));
                if constexpr (KSEG == 192) {
                    e8  += bf2f((unsigned short)(u.x & 0xffff));
                    e9  += bf2f((unsigned short)(u.x >> 16));
                    e10 += bf2f((unsigned short)(u.y & 0xffff));
                    e11 += bf2f((unsigned short)(u.y >> 16));
                }
            };
            auto PK = [](float lo, float hi) {
                return (unsigned)(unsigned short)f2bf(lo) |
                       ((unsigned)(unsigned short)f2bf(hi) << 16);
            };
            auto FLUSH = [&]() {
                float w = sMW[sg * 128 + local0 + di];
                int zr = (local0 + di) * SA;
                uint4 pv;
                pv.x = PK(a0 * w, a1 * w); pv.y = PK(a2 * w, a3 * w);
                pv.z = PK(a4 * w, a5 * w); pv.w = PK(a6 * w, a7 * w);
                *(uint4*)&Zs[zr + l16 * 8] = pv;
                if constexpr (KSEG == 192) {
                    if (l16 < 10) {                // packed cols 128..167
                        uint2 q; q.x = PK(e8 * w, e9 * w); q.y = PK(e10 * w, e11 * w);
                        *(uint2*)&Zs[zr + 128 + l16 * 4] = q;
                    }
                    e8 = 0.f; e9 = 0.f; e10 = 0.f; e11 = 0.f;
                }
                a0 = 0.f; a1 = 0.f; a2 = 0.f; a3 = 0.f;
                a4 = 0.f; a5 = 0.f; a6 = 0.f; a7 = 0.f;
            };

            if (jlo < jhi) LD(jlo, vA, uA);
            if (jlo + 1 < jhi) LD(jlo + 1, vB, uB);
            int j = jlo;
            while (true) {
                while (di < 4 && j == nextb) {
                    FLUSH(); di++;
                    nextb = (di < 4) ? sMS[sg * 129 + local0 + di + 1] : 0x7fffffff;
                }
                if (j >= jhi) break;
                CONSUME(vA, uA);
                if (j + 2 < jhi) LD(j + 2, vA, uA);
                j++;
                while (di < 4 && j == nextb) {
                    FLUSH(); di++;
                    nextb = (di < 4) ? sMS[sg * 129 + local0 + di + 1] : 0x7fffffff;
                }
                if (j >= jhi) break;
                CONSUME(vB, uB);
                if (j + 2 < jhi) LD(j + 2, vB, uB);
                j++;
            }
        }
        __syncthreads();      // Z tile staged

        // ---- MFMA from Zs (cols >= packed width have zero weights) ----
        #pragma unroll
        for (int k = 0; k < KS; k++) {
            if (k + 1 < KS) {
                #pragma unroll
                for (int j = 0; j < 4; j++)
                    bn[j] = *(const bf16x8*)(Bp + (size_t)j * 16 * KCAT + (tb + k + 1) * 32);
            }
            #pragma unroll
            for (int i = 0; i < 2; i++)
                ac[i] = *(const bf16x8*)&Zs[(wr0 + i * 16 + l16) * SA + k * 32 + quad * 8];
            #pragma unroll
            for (int i = 0; i < 2; i++)
                #pragma unroll
                for (int j = 0; j < 4; j++)
                    acc[i][j] = __builtin_amdgcn_mfma_f32_16x16x32_bf16(ac[i], bc[j], acc[i][j], 0, 0, 0);
            if (k + 1 < KS) {
                #pragma unroll
                for (int j = 0; j < 4; j++) bc[j] = bn[j];
            }
        }
        __syncthreads();      // all waves done with Zs before next gather
    }

    // ---- fused bias + relu -> LDS (stride 136) -> coalesced bf16x8 stores ----
    float bj[4];
    #pragma unroll
    for (int j = 0; j < 4; j++) bj[j] = bias[wc0 + j * 16 + l16];
    #pragma unroll
    for (int i = 0; i < 2; i++)
        #pragma unroll
        for (int j = 0; j < 4; j++)
            #pragma unroll
            for (int reg = 0; reg < 4; reg++)
                Zs[(wr0 + i * 16 + quad * 4 + reg) * 136 + wc0 + j * 16 + l16] =
                    f2bf(fmaxf(acc[i][j][reg] + bj[j], 0.f));
    __syncthreads();

    #pragma unroll
    for (int s = 0; s < 4; s++) {
        int row = (tid >> 4) + s * 32;
        int col = (tid & 15) * 8;
        bf16x8 v = *(const bf16x8*)&Zs[row * 136 + col];
        *(bf16x8*)&Hout[(size_t)(row0 + row) * HID + col] = v;
    }
}

// ---------------- readout ----------------
__global__ __launch_bounds__(128)
void k_pool(const unsigned short* __restrict__ h, const int* __restrict__ batch,
            float* __restrict__ pooled) {
    int c = threadIdx.x;
    int start = blockIdx.x * 128;
    if (start >= N_NODES) return;
    int end = min(start + 128, N_NODES);
    int g = batch[start];
    float s = 0.f;
    for (int i = start; i < end; i++) {
        int gi = batch[i];
        if (gi != g) { atomicAdd(&pooled[g * HID + c], s); s = 0.f; g = gi; }
        s += bf2f(h[(size_t)i * HID + c]);
    }
    atomicAdd(&pooled[g * HID + c], s);
}

__device__ int lower_bound_i(const int* a, int n, int v) {
    int lo = 0, hi = n;
    while (lo < hi) {
        int mid = (lo + hi) >> 1;
        if (a[mid] < v) lo = mid + 1; else hi = mid;
    }
    return lo;
}

__global__ __launch_bounds__(128)
void k_mlp(const float* __restrict__ pooled, const int* __restrict__ batch,
           const float* __restrict__ Wc1, const float* __restrict__ bc1,
           const float* __restrict__ Wc2, const float* __restrict__ bc2,
           const float* __restrict__ Wc3, const float* __restrict__ bc3,
           float* __restrict__ out) {
    int g = blockIdx.x;
    int c = threadIdx.x;
    __shared__ int range[2];
    if (c == 0) range[0] = lower_bound_i(batch, N_NODES, g);
    if (c == 1) range[1] = lower_bound_i(batch, N_NODES, g + 1);
    __syncthreads();
    float denom = fmaxf((float)(range[1] - range[0]), 1.0f);
    __shared__ float row[HID], h1[HID], h2[HID];
    row[c] = pooled[g * HID + c] / denom;
    __syncthreads();
    float acc = bc1[c];
    for (int k = 0; k < HID; k++) acc += row[k] * Wc1[k * HID + c];
    h1[c] = fmaxf(acc, 0.f);
    __syncthreads();
    acc = bc2[c];
    for (int k = 0; k < HID; k++) acc += h1[k] * Wc2[k * HID + c];
    h2[c] = fmaxf(acc, 0.f);
    __syncthreads();
    float t = h2[c] * Wc3[c];
    for (int off = 32; off > 0; off >>= 1) t += __shfl_down(t, off, 64);
    __shared__ float part[2];
    if ((c & 63) == 0) part[c >> 6] = t;
    __syncthreads();
    if (c == 0) out[g] = part[0] + part[1] + bc3[0];
}

// ---------------- launcher ----------------
extern "C" void kernel_launch(void* const* d_in, const int* in_sizes, int n_in,
                              void* d_out, int out_size, void* d_ws, size_t ws_size,
                              hipStream_t stream) {
    const float* X     = (const float*)d_in[0];
    const int*   batch = (const int*)d_in[1];
    const int*   e0 = (const int*)d_in[2];
    const int*   e1 = (const int*)d_in[3];
    const int*   e2 = (const int*)d_in[4];
    const int*   e3 = (const int*)d_in[5];
    const int*   e4 = (const int*)d_in[6];
    const float* W0    = (const float*)d_in[7];
    const float* root0 = (const float*)d_in[8];
    const float* b0    = (const float*)d_in[9];
    const float* Wl    = (const float*)d_in[10];
    const float* rootl = (const float*)d_in[11];
    const float* bl    = (const float*)d_in[12];
    const float* Wc1   = (const float*)d_in[13];
    const float* bc1   = (const float*)d_in[14];
    const float* Wc2   = (const float*)d_in[15];
    const float* bc2   = (const float*)d_in[16];
    const float* Wc3   = (const float*)d_in[17];
    const float* bc3   = (const float*)d_in[18];
    const int E = in_sizes[2] / 2;
    const int NE = R_REL * E;

    char* base = (char*)d_ws;
    size_t o = 0;
    auto carve = [&](size_t bytes) -> char* {
        char* p = base + o;
        o = (o + bytes + 255) & ~(size_t)255;
        return p;
    };
    // No Z buffer at all: total ~75 MB.
    unsigned short* h1 = (unsigned short*)carve((size_t)NPAD * HID * 2);    // also h3
    unsigned short* Xb = (unsigned short*)carve((size_t)NPAD * KSEG0 * 2);  // also h2
    int*   cnt    = (int*)carve((size_t)M5 * 4);
    float* invc   = (float*)carve((size_t)M5 * 4);
    int*   offsc  = (int*)carve((size_t)M5 * 4);
    int*   mstart = (int*)carve((size_t)(M5 + 1) * 4);
    int*   mrec   = (int*)carve((size_t)NE * 4);
    int*   bsum   = (int*)carve(2048);
    float* pooled = (float*)carve((size_t)G_GRAPHS * HID * 4);
    short* Wt0    = (short*)carve((size_t)128 * KC0 * 2);
    short* Wtl    = (short*)carve((size_t)L_LAYERS * 128 * KC1 * 2);
    int*   mcur   = offsc;                 // offsc dead after k_scan3
    unsigned short* h2 = Xb;               // Xb dead after layer-0 GEMM

    // ---- CSR build + casts + weight transposes ----
    hipMemsetAsync(cnt, 0, (size_t)M5 * 4, stream);
    hipMemsetAsync(pooled, 0, (size_t)G_GRAPHS * HID * 4, stream);
    int eg = (NE + 255) / 256;
    k_count<<<eg, 256, 0, stream>>>(e0, e1, e2, e3, e4, cnt, E);
    int nblk = (M5 + 1023) / 1024;   // 489
    k_scan1<<<nblk, 256, 0, stream>>>(cnt, offsc, bsum);
    k_scan2<<<1, 512, 0, stream>>>(bsum, nblk);
    k_scan3<<<(M5 + 255) / 256, 256, 0, stream>>>(offsc, bsum, mstart, mcur, cnt, invc);
    k_fill<<<eg, 256, 0, stream>>>(e0, e1, e2, e3, e4, mcur, mrec, E);
    k_castX<<<(NPAD * KSEG0 + 255) / 256, 256, 0, stream>>>(X, Xb);
    k_tw0<<<(128 * KC0 + 255) / 256, 256, 0, stream>>>(root0, W0, Wt0);
    k_twl<<<(L_LAYERS * 128 * KC1 + 255) / 256, 256, 0, stream>>>(rootl, Wl, Wtl);

    // ---- three fused gather+GEMM layers (512 threads / 8 waves per block) ----
    gemm_fused<KSEG0><<<NTILES, 512, 0, stream>>>(Xb, Wt0, b0, mstart, mrec, invc, h1);
    gemm_fused<HID><<<NTILES, 512, 0, stream>>>(h1, Wtl, bl, mstart, mrec, invc, h2);
    gemm_fused<HID><<<NTILES, 512, 0, stream>>>(h2, Wtl + (size_t)128 * KC1, bl + HID,
                                                mstart, mrec, invc, h1);

    // ---- readout ----
    k_pool<<<(N_NODES + 127) / 128, 128, 0, stream>>>(h1, batch, pooled);
    k_mlp<<<G_GRAPHS, 128, 0, stream>>>(pooled, batch, Wc1, bc1, Wc2, bc2, Wc3, bc3, (float*)d_out);
}

// Round 11
// 726.910 us; speedup vs baseline: 1.2326x; 1.2326x over previous
//
#include <hip/hip_runtime.h>

#define N_NODES 100000
#define NPAD    100096      // 782 * 128
#define NTILES  782
#define G_GRAPHS 256
#define IN_F 162
#define HID 128
#define R_REL 5
#define L_LAYERS 2
#define M5 (R_REL * N_NODES)
#define KSEG0 192           // layer-0 segment width (162 padded to 192)
#define KC0   (6 * KSEG0)   // 1152 : logical K of layer-0 GEMM
#define KC1   (6 * HID)     // 768  : logical K of layer-1/2 GEMM

typedef __attribute__((ext_vector_type(8))) short bf16x8;
typedef __attribute__((ext_vector_type(4))) float f32x4;

__device__ __forceinline__ short f2bf(float f) {
    union { float f; unsigned u; } v; v.f = f;
    unsigned r = (v.u + 0x7fffu + ((v.u >> 16) & 1u)) >> 16;
    return (short)r;
}
__device__ __forceinline__ float bf2f(unsigned short u) {
    union { unsigned u; float f; } v; v.u = ((unsigned)u) << 16;
    return v.f;
}

// ---------------- CSR build, keyed by (relation, dst) ----------------
__global__ void k_count(const int* e0, const int* e1, const int* e2,
                        const int* e3, const int* e4, int* cnt, int E) {
    int gid = blockIdx.x * 256 + threadIdx.x;
    if (gid >= R_REL * E) return;
    int r = gid / E, e = gid - r * E;
    const int* ei = (r == 0) ? e0 : (r == 1) ? e1 : (r == 2) ? e2 : (r == 3) ? e3 : e4;
    atomicAdd(&cnt[r * N_NODES + ei[E + e]], 1);
}

__global__ __launch_bounds__(256) void k_scan1(const int* __restrict__ cnt,
                                               int* __restrict__ off, int* __restrict__ bsum) {
    __shared__ int ts[256];
    int t = threadIdx.x;
    int base = blockIdx.x * 1024 + t * 4;
    int v[4];
    #pragma unroll
    for (int j = 0; j < 4; j++) v[j] = (base + j < M5) ? cnt[base + j] : 0;
    int tsum = v[0] + v[1] + v[2] + v[3];
    ts[t] = tsum; __syncthreads();
    for (int o = 1; o < 256; o <<= 1) {
        int x = (t >= o) ? ts[t - o] : 0;
        __syncthreads();
        ts[t] += x;
        __syncthreads();
    }
    if (t == 255) bsum[blockIdx.x] = ts[255];
    int run = ts[t] - tsum;
    #pragma unroll
    for (int j = 0; j < 4; j++) { if (base + j < M5) off[base + j] = run; run += v[j]; }
}

__global__ __launch_bounds__(512) void k_scan2(int* bsum, int nblk) {
    __shared__ int ts[512];
    int t = threadIdx.x;
    int v = (t < nblk) ? bsum[t] : 0;
    ts[t] = v; __syncthreads();
    for (int o = 1; o < 512; o <<= 1) {
        int x = (t >= o) ? ts[t - o] : 0;
        __syncthreads();
        ts[t] += x;
        __syncthreads();
    }
    if (t < nblk) bsum[t] = ts[t] - v;   // exclusive
}

__global__ void k_scan3(const int* __restrict__ off, const int* __restrict__ bsum,
                        int* __restrict__ mstart, int* __restrict__ mcur,
                        const int* __restrict__ cnt, float* __restrict__ invc) {
    int i = blockIdx.x * 256 + threadIdx.x;
    if (i >= M5) return;
    int o = off[i] + bsum[i >> 10];
    mstart[i] = o;
    mcur[i] = o;
    int c = cnt[i];
    invc[i] = 1.0f / (float)max(c, 1);
    if (i == M5 - 1) mstart[M5] = o + c;
}

__global__ void k_fill(const int* e0, const int* e1, const int* e2,
                       const int* e3, const int* e4, int* mcur,
                       int* __restrict__ mrec, int E) {
    int gid = blockIdx.x * 256 + threadIdx.x;
    if (gid >= R_REL * E) return;
    int r = gid / E, e = gid - r * E;
    const int* ei = (r == 0) ? e0 : (r == 1) ? e1 : (r == 2) ? e2 : (r == 3) ? e3 : e4;
    int src = ei[e], dst = ei[E + e];
    int pos = atomicAdd(&mcur[r * N_NODES + dst], 1);
    mrec[pos] = src;
}

// ---------------- X fp32 -> bf16, padded [NPAD][192] ----------------
__global__ void k_castX(const float* __restrict__ X, unsigned short* __restrict__ Xb) {
    int gid = blockIdx.x * 256 + threadIdx.x;
    if (gid >= NPAD * KSEG0) return;
    int row = gid / KSEG0, k = gid - row * KSEG0;
    float v = (row < N_NODES && k < IN_F) ? X[(size_t)row * IN_F + k] : 0.f;
    Xb[gid] = (unsigned short)f2bf(v);
}

// ---------------- weight transpose: Wt[col][KCAT] with seg-concat K ----------------
__global__ void k_tw0(const float* __restrict__ root0, const float* __restrict__ W0,
                      short* __restrict__ out) {
    int gid = blockIdx.x * 256 + threadIdx.x;   // 128 * 1152
    if (gid >= 128 * KC0) return;
    int col = gid / KC0;
    int kk = gid - col * KC0;
    int chunk = kk / KSEG0, k = kk - chunk * KSEG0;
    float v = 0.f;
    if (k < IN_F)
        v = (chunk == 0) ? root0[k * HID + col]
                         : W0[((size_t)(chunk - 1) * IN_F + k) * HID + col];
    out[gid] = f2bf(v);
}

__global__ void k_twl(const float* __restrict__ rootl, const float* __restrict__ Wl,
                      short* __restrict__ out) {
    int gid = blockIdx.x * 256 + threadIdx.x;   // 2 * 128 * 768
    if (gid >= L_LAYERS * 128 * KC1) return;
    int l = gid / (128 * KC1);
    int rem = gid - l * 128 * KC1;
    int col = rem / KC1;
    int kk = rem - col * KC1;
    int chunk = kk / HID, k = kk - chunk * HID;
    float v = (chunk == 0) ? rootl[((size_t)l * HID + k) * HID + col]
                           : Wl[(((size_t)l * R_REL + (chunk - 1)) * HID + k) * HID + col];
    out[gid] = f2bf(v);
}

// ---------------- fused gather+GEMM, wave-uniform batched gather ----------------
// h'[row][0:128] = relu( [A0 | Z1..Z5] @ Wt^T + bias ). Z never hits global.
// Gather (r0-aggregate's proven pattern, in-block): each wave owns 32 consecutive
// dsts per segment; full-wave 64-lane x 4B row loads; per batch, 8 INDEPENDENT
// row loads issue into named registers before any consume, so ~8 loads stay in
// flight per wave (counted vmcnt by the compiler). Edge indices + CSR meta in LDS;
// boundary flushes are wave-uniform. Zero divergence, no dependent chains.
template<int KSEG>
__global__ __launch_bounds__(256)
void gemm_fused(const unsigned short* __restrict__ A0, const short* __restrict__ Wt,
                const float* __restrict__ bias,
                const int* __restrict__ mstart, const int* __restrict__ mrec,
                const float* __restrict__ invc,
                unsigned short* __restrict__ Hout) {
    constexpr int KS = KSEG / 32;                 // k-steps per segment (6 or 4)
    constexpr int KCAT = 6 * KSEG;
    constexpr int SA = (KSEG == 192) ? 184 : 136; // Z-tile LDS row stride (shorts)
    constexpr int EBUF = 384;                     // staged edge indices per segment
    __shared__ short Zs[128 * SA + 16];           // +16: L0 k=5 quad=3 read spill
    __shared__ int   sMS[5 * 129];                // mstart slices (block dsts, 5 segs)
    __shared__ float sMW[5 * 128];                // invc slices
    __shared__ int   sE[EBUF];                    // per-segment edge indices

    const int row0 = blockIdx.x * 128;
    const int tid = threadIdx.x;
    const int lane = tid & 63, wv = tid >> 6;     // 4 waves
    const int quad = lane >> 4, l16 = lane & 15;
    const int wr0 = (wv >> 1) * 64, wc0 = (wv & 1) * 64;

    // ---- stage CSR meta for the whole block (overlaps seg0 MFMA) ----
    for (int i = tid; i < 5 * 129; i += 256) {
        int seg = i / 129, o = i - seg * 129;
        sMS[i] = mstart[seg * N_NODES + min(row0 + o, N_NODES)];
    }
    for (int i = tid; i < 5 * 128; i += 256) {
        int seg = i >> 7, o = i & 127;
        int d = row0 + o;
        sMW[i] = (d < N_NODES) ? invc[seg * N_NODES + d] : 0.f;
    }
    if constexpr (KSEG == 192) {                  // zero L0's unwritten cols + pad
        for (int i = tid; i < 128 * 16; i += 256)
            Zs[(i >> 4) * SA + 168 + (i & 15)] = 0;
        if (tid < 16) Zs[128 * SA + tid] = 0;
    }

    const unsigned short* a0p = A0 + (size_t)(row0 + wr0 + l16) * KSEG + quad * 8;
    const short* Bp = Wt + (size_t)(wc0 + l16) * KCAT + quad * 8;

    f32x4 acc[4][4];
    #pragma unroll
    for (int i = 0; i < 4; i++)
        #pragma unroll
        for (int j = 0; j < 4; j++) acc[i][j] = (f32x4){0.f, 0.f, 0.f, 0.f};

    // ---- seg0: root term, A direct from global, 1-deep register dbuf ----
    bf16x8 ac[4], bc[4], an[4], bn[4];
    #pragma unroll
    for (int i = 0; i < 4; i++) {
        ac[i] = *(const bf16x8*)(a0p + (size_t)i * 16 * KSEG);
        bc[i] = *(const bf16x8*)(Bp + (size_t)i * 16 * KCAT);
    }
    #pragma unroll
    for (int t = 0; t < KS; t++) {
        if (t + 1 < KS) {
            #pragma unroll
            for (int i = 0; i < 4; i++) {
                an[i] = *(const bf16x8*)(a0p + (size_t)i * 16 * KSEG + (t + 1) * 32);
                bn[i] = *(const bf16x8*)(Bp + (size_t)i * 16 * KCAT + (t + 1) * 32);
            }
        }
        #pragma unroll
        for (int i = 0; i < 4; i++)
            #pragma unroll
            for (int j = 0; j < 4; j++)
                acc[i][j] = __builtin_amdgcn_mfma_f32_16x16x32_bf16(ac[i], bc[j], acc[i][j], 0, 0, 0);
        if (t + 1 < KS) {
            #pragma unroll
            for (int i = 0; i < 4; i++) { ac[i] = an[i]; bc[i] = bn[i]; }
        }
    }
    __syncthreads();   // meta (and L0 zero-cols) staged

    // ---- relation segments ----
    for (int sg = 0; sg < R_REL; sg++) {
        const int tb = (1 + sg) * KS;
        #pragma unroll
        for (int j = 0; j < 4; j++)
            bc[j] = *(const bf16x8*)(Bp + (size_t)j * 16 * KCAT + tb * 32);

        // stage this segment's edge-index run (contiguous in mrec) into LDS
        const int blo = sMS[sg * 129];
        {
            int cnt = sMS[sg * 129 + 128] - blo;
            if (cnt > EBUF) cnt = EBUF;
            for (int i = tid; i < cnt; i += 256) sE[i] = mrec[blo + i];
        }
        __syncthreads();   // sE ready; prior MFMA done reading Zs

        // ---- gather: wave-uniform batched-8 edge walk, 32 dsts per wave ----
        {
            const int mbase = sg * 129 + wv * 32;
            const int jlo = sMS[mbase];
            const int jhi = sMS[mbase + 32];
            int di = 0;
            int bnd = sMS[mbase + 1];
            float s0 = 0.f, s1 = 0.f, s2 = 0.f, s3 = 0.f;
            const int lx = (lane & 31) * 2;       // L0 extra-col lane offset

            auto FLUSH = [&]() {
                float w = sMW[sg * 128 + wv * 32 + di];
                int zr = (wv * 32 + di) * SA;
                unsigned pv = (unsigned)(unsigned short)f2bf(s0 * w) |
                              ((unsigned)(unsigned short)f2bf(s1 * w) << 16);
                *(unsigned*)&Zs[zr + lane * 2] = pv;
                if constexpr (KSEG == 192) {
                    if (lane < 20) {              // packed cols 128..167
                        unsigned qv = (unsigned)(unsigned short)f2bf(s2 * w) |
                                      ((unsigned)(unsigned short)f2bf(s3 * w) << 16);
                        *(unsigned*)&Zs[zr + 128 + lane * 2] = qv;
                    }
                }
                s0 = 0.f; s1 = 0.f; s2 = 0.f; s3 = 0.f;
            };

            #define GLD(i, q, u) { \
                int j_ = min(jb + i, jmax); int jj_ = j_ - blo; \
                int src_ = (jj_ < EBUF) ? sE[jj_] : mrec[j_]; \
                const unsigned short* r_ = A0 + (size_t)src_ * KSEG; \
                q = *(const unsigned*)(r_ + lane * 2); \
                if constexpr (KSEG == 192) u = *(const unsigned*)(r_ + 128 + lx); }

            #define CNS(i, q, u) if (jb + i < jhi) { \
                int j_ = jb + i; \
                while (di < 32 && j_ == bnd) { \
                    FLUSH(); di++; \
                    bnd = (di < 32) ? sMS[mbase + di + 1] : 0x7fffffff; \
                } \
                s0 += bf2f((unsigned short)(q & 0xffff)); \
                s1 += bf2f((unsigned short)(q >> 16)); \
                if constexpr (KSEG == 192) { \
                    s2 += bf2f((unsigned short)(u & 0xffff)); \
                    s3 += bf2f((unsigned short)(u >> 16)); } }

            for (int jb = jlo; jb < jhi; jb += 8) {
                const int jmax = jhi - 1;
                unsigned q0, q1, q2, q3, q4, q5, q6, q7;
                unsigned u0 = 0, u1 = 0, u2 = 0, u3 = 0, u4 = 0, u5 = 0, u6 = 0, u7 = 0;
                GLD(0, q0, u0) GLD(1, q1, u1) GLD(2, q2, u2) GLD(3, q3, u3)
                GLD(4, q4, u4) GLD(5, q5, u5) GLD(6, q6, u6) GLD(7, q7, u7)
                CNS(0, q0, u0) CNS(1, q1, u1) CNS(2, q2, u2) CNS(3, q3, u3)
                CNS(4, q4, u4) CNS(5, q5, u5) CNS(6, q6, u6) CNS(7, q7, u7)
            }
            while (di < 32) { FLUSH(); di++; }
            #undef GLD
            #undef CNS
        }
        __syncthreads();      // Z tile staged

        // ---- MFMA from Zs (cols >= packed width have zero weights) ----
        #pragma unroll
        for (int k = 0; k < KS; k++) {
            if (k + 1 < KS) {
                #pragma unroll
                for (int j = 0; j < 4; j++)
                    bn[j] = *(const bf16x8*)(Bp + (size_t)j * 16 * KCAT + (tb + k + 1) * 32);
            }
            #pragma unroll
            for (int i = 0; i < 4; i++)
                ac[i] = *(const bf16x8*)&Zs[(wr0 + i * 16 + l16) * SA + k * 32 + quad * 8];
            #pragma unroll
            for (int i = 0; i < 4; i++)
                #pragma unroll
                for (int j = 0; j < 4; j++)
                    acc[i][j] = __builtin_amdgcn_mfma_f32_16x16x32_bf16(ac[i], bc[j], acc[i][j], 0, 0, 0);
            if (k + 1 < KS) {
                #pragma unroll
                for (int j = 0; j < 4; j++) bc[j] = bn[j];
            }
        }
        __syncthreads();      // all waves done with Zs before next gather
    }

    // ---- fused bias + relu -> LDS (stride 136) -> coalesced bf16x8 stores ----
    float bj[4];
    #pragma unroll
    for (int j = 0; j < 4; j++) bj[j] = bias[wc0 + j * 16 + l16];
    #pragma unroll
    for (int i = 0; i < 4; i++)
        #pragma unroll
        for (int j = 0; j < 4; j++)
            #pragma unroll
            for (int reg = 0; reg < 4; reg++)
                Zs[(wr0 + i * 16 + quad * 4 + reg) * 136 + wc0 + j * 16 + l16] =
                    f2bf(fmaxf(acc[i][j][reg] + bj[j], 0.f));
    __syncthreads();

    #pragma unroll
    for (int s = 0; s < 8; s++) {
        int row = (tid >> 4) + s * 16;
        int col = (tid & 15) * 8;
        bf16x8 v = *(const bf16x8*)&Zs[row * 136 + col];
        *(bf16x8*)&Hout[(size_t)(row0 + row) * HID + col] = v;
    }
}

// ---------------- readout ----------------
__global__ __launch_bounds__(128)
void k_pool(const unsigned short* __restrict__ h, const int* __restrict__ batch,
            float* __restrict__ pooled) {
    int c = threadIdx.x;
    int start = blockIdx.x * 128;
    if (start >= N_NODES) return;
    int end = min(start + 128, N_NODES);
    int g = batch[start];
    float s = 0.f;
    for (int i = start; i < end; i++) {
        int gi = batch[i];
        if (gi != g) { atomicAdd(&pooled[g * HID + c], s); s = 0.f; g = gi; }
        s += bf2f(h[(size_t)i * HID + c]);
    }
    atomicAdd(&pooled[g * HID + c], s);
}

__device__ int lower_bound_i(const int* a, int n, int v) {
    int lo = 0, hi = n;
    while (lo < hi) {
        int mid = (lo + hi) >> 1;
        if (a[mid] < v) lo = mid + 1; else hi = mid;
    }
    return lo;
}

__global__ __launch_bounds__(128)
void k_mlp(const float* __restrict__ pooled, const int* __restrict__ batch,
           const float* __restrict__ Wc1, const float* __restrict__ bc1,
           const float* __restrict__ Wc2, const float* __restrict__ bc2,
           const float* __restrict__ Wc3, const float* __restrict__ bc3,
           float* __restrict__ out) {
    int g = blockIdx.x;
    int c = threadIdx.x;
    __shared__ int range[2];
    if (c == 0) range[0] = lower_bound_i(batch, N_NODES, g);
    if (c == 1) range[1] = lower_bound_i(batch, N_NODES, g + 1);
    __syncthreads();
    float denom = fmaxf((float)(range[1] - range[0]), 1.0f);
    __shared__ float row[HID], h1[HID], h2[HID];
    row[c] = pooled[g * HID + c] / denom;
    __syncthreads();
    float acc = bc1[c];
    for (int k = 0; k < HID; k++) acc += row[k] * Wc1[k * HID + c];
    h1[c] = fmaxf(acc, 0.f);
    __syncthreads();
    acc = bc2[c];
    for (int k = 0; k < HID; k++) acc += h1[k] * Wc2[k * HID + c];
    h2[c] = fmaxf(acc, 0.f);
    __syncthreads();
    float t = h2[c] * Wc3[c];
    for (int off = 32; off > 0; off >>= 1) t += __shfl_down(t, off, 64);
    __shared__ float part[2];
    if ((c & 63) == 0) part[c >> 6] = t;
    __syncthreads();
    if (c == 0) out[g] = part[0] + part[1] + bc3[0];
}

// ---------------- launcher ----------------
extern "C" void kernel_launch(void* const* d_in, const int* in_sizes, int n_in,
                              void* d_out, int out_size, void* d_ws, size_t ws_size,
                              hipStream_t stream) {
    const float* X     = (const float*)d_in[0];
    const int*   batch = (const int*)d_in[1];
    const int*   e0 = (const int*)d_in[2];
    const int*   e1 = (const int*)d_in[3];
    const int*   e2 = (const int*)d_in[4];
    const int*   e3 = (const int*)d_in[5];
    const int*   e4 = (const int*)d_in[6];
    const float* W0    = (const float*)d_in[7];
    const float* root0 = (const float*)d_in[8];
    const float* b0    = (const float*)d_in[9];
    const float* Wl    = (const float*)d_in[10];
    const float* rootl = (const float*)d_in[11];
    const float* bl    = (const float*)d_in[12];
    const float* Wc1   = (const float*)d_in[13];
    const float* bc1   = (const float*)d_in[14];
    const float* Wc2   = (const float*)d_in[15];
    const float* bc2   = (const float*)d_in[16];
    const float* Wc3   = (const float*)d_in[17];
    const float* bc3   = (const float*)d_in[18];
    const int E = in_sizes[2] / 2;
    const int NE = R_REL * E;

    char* base = (char*)d_ws;
    size_t o = 0;
    auto carve = [&](size_t bytes) -> char* {
        char* p = base + o;
        o = (o + bytes + 255) & ~(size_t)255;
        return p;
    };
    // No Z buffer at all: total ~75 MB.
    unsigned short* h1 = (unsigned short*)carve((size_t)NPAD * HID * 2);    // also h3
    unsigned short* Xb = (unsigned short*)carve((size_t)NPAD * KSEG0 * 2);  // also h2
    int*   cnt    = (int*)carve((size_t)M5 * 4);
    float* invc   = (float*)carve((size_t)M5 * 4);
    int*   offsc  = (int*)carve((size_t)M5 * 4);
    int*   mstart = (int*)carve((size_t)(M5 + 1) * 4);
    int*   mrec   = (int*)carve((size_t)NE * 4);
    int*   bsum   = (int*)carve(2048);
    float* pooled = (float*)carve((size_t)G_GRAPHS * HID * 4);
    short* Wt0    = (short*)carve((size_t)128 * KC0 * 2);
    short* Wtl    = (short*)carve((size_t)L_LAYERS * 128 * KC1 * 2);
    int*   mcur   = offsc;                 // offsc dead after k_scan3
    unsigned short* h2 = Xb;               // Xb dead after layer-0 GEMM

    // ---- CSR build + casts + weight transposes ----
    hipMemsetAsync(cnt, 0, (size_t)M5 * 4, stream);
    hipMemsetAsync(pooled, 0, (size_t)G_GRAPHS * HID * 4, stream);
    int eg = (NE + 255) / 256;
    k_count<<<eg, 256, 0, stream>>>(e0, e1, e2, e3, e4, cnt, E);
    int nblk = (M5 + 1023) / 1024;   // 489
    k_scan1<<<nblk, 256, 0, stream>>>(cnt, offsc, bsum);
    k_scan2<<<1, 512, 0, stream>>>(bsum, nblk);
    k_scan3<<<(M5 + 255) / 256, 256, 0, stream>>>(offsc, bsum, mstart, mcur, cnt, invc);
    k_fill<<<eg, 256, 0, stream>>>(e0, e1, e2, e3, e4, mcur, mrec, E);
    k_castX<<<(NPAD * KSEG0 + 255) / 256, 256, 0, stream>>>(X, Xb);
    k_tw0<<<(128 * KC0 + 255) / 256, 256, 0, stream>>>(root0, W0, Wt0);
    k_twl<<<(L_LAYERS * 128 * KC1 + 255) / 256, 256, 0, stream>>>(rootl, Wl, Wtl);

    // ---- three fused gather+GEMM layers ----
    gemm_fused<KSEG0><<<NTILES, 256, 0, stream>>>(Xb, Wt0, b0, mstart, mrec, invc, h1);
    gemm_fused<HID><<<NTILES, 256, 0, stream>>>(h1, Wtl, bl, mstart, mrec, invc, h2);
    gemm_fused<HID><<<NTILES, 256, 0, stream>>>(h2, Wtl + (size_t)128 * KC1, bl + HID,
                                                mstart, mrec, invc, h1);

    // ---- readout ----
    k_pool<<<(N_NODES + 127) / 128, 128, 0, stream>>>(h1, batch, pooled);
    k_mlp<<<G_GRAPHS, 128, 0, stream>>>(pooled, batch, Wc1, bc1, Wc2, bc2, Wc3, bc3, (float*)d_out);
}